// Round 13
// baseline (4194.735 us; speedup 1.0000x reference)
//
#include <hip/hip_runtime.h>
#include <hip/hip_bf16.h>
#include <math.h>
#include <stdint.h>

// RNN LM forward: B=64 T=512 V=8192 E=1024 H=2048
// out = [logits (B*T*V f32) | loss (1 f32)]
#define Bb 64
#define Tt 512
#define Vv 8192
#define Ee 1024
#define Hh 2048

typedef unsigned short u16;
typedef unsigned long long u64;
typedef __attribute__((ext_vector_type(8))) short bf16x8;      // 8x16b (4 VGPR)
typedef __attribute__((ext_vector_type(8))) _Float16 f16x8;    // 8 f16  (4 VGPR)
typedef __attribute__((ext_vector_type(4))) float f32x4;       // MFMA C/D frag

__device__ __forceinline__ u16 f2b(float f) {               // f32 -> bf16 RNE
  unsigned u = __float_as_uint(f);
  u += 0x7FFF + ((u >> 16) & 1);
  return (u16)(u >> 16);
}
__device__ __forceinline__ float b2f(u16 h) {
  return __uint_as_float(((unsigned)h) << 16);
}
__device__ __forceinline__ u16 f2h_bits(float f) {          // f32 -> f16 bits
  union { _Float16 h; u16 u; } c;
  c.h = (_Float16)f;
  return c.u;
}

// pipelined agent-coherent 16B load (sc1 = bypass XCD-L2, read L3 directly)
__device__ __forceinline__ void gload16f(f16x8& dst, const void* addr) {
  asm volatile("global_load_dwordx4 %0, %1, off sc1"
               : "=v"(dst) : "v"(addr) : "memory");
}
// agent-coherent 2B store (same semantics as relaxed agent atomic store)
__device__ __forceinline__ void gstore2_sc1(void* addr, unsigned val) {
  asm volatile("global_store_short %0, %1, off sc1"
               :: "v"(addr), "v"(val) : "memory");
}

__device__ __forceinline__ void gll16(const u16* g, const u16* l) {
  __builtin_amdgcn_global_load_lds((__attribute__((address_space(1))) void*)g,
                                   (__attribute__((address_space(3))) void*)l, 16, 0, 0);
}

__device__ __forceinline__ float wave_max(float v) {
  #pragma unroll
  for (int d = 32; d; d >>= 1) v = fmaxf(v, __shfl_xor(v, d, 64));
  return v;
}
__device__ __forceinline__ float wave_sum(float v) {
  #pragma unroll
  for (int d = 32; d; d >>= 1) v += __shfl_xor(v, d, 64);
  return v;
}

// ---------------- fused prep kernel ----------------
// one launch, sectioned by blockIdx:
//  [0, 32768)              embed gather -> f16
//  [32768, 34816)          Wx  transpose f16 (grid 64 x 32)
//  [34816, 38912)          Wh  transpose f16 (grid 64 x 64)
//  [38912, 55296)          Whead transpose f16 (grid 256 x 64)
//  [55296, 55360)          h0 init (64 blocks) + sync zero (block 0)

__device__ __forceinline__ void tr_cast_f16(const float* __restrict__ src,
                                            u16* __restrict__ dst, int R, int C,
                                            int bi, int bj, int tid,
                                            float (*tile)[33]) {
  const int r  = tid >> 3;
  const int c4 = (tid & 7) * 4;
  float4 v = *(const float4*)(src + (size_t)(bj * 32 + r) * C + bi * 32 + c4);
  tile[r][c4 + 0] = v.x; tile[r][c4 + 1] = v.y;
  tile[r][c4 + 2] = v.z; tile[r][c4 + 3] = v.w;
  __syncthreads();
  ushort4 o;
  o.x = f2h_bits(tile[c4 + 0][r]); o.y = f2h_bits(tile[c4 + 1][r]);
  o.z = f2h_bits(tile[c4 + 2][r]); o.w = f2h_bits(tile[c4 + 3][r]);
  *(ushort4*)(dst + (size_t)(bi * 32 + r) * R + bj * 32 + c4) = o;
}

__global__ __launch_bounds__(256)
void prep_all(const float* __restrict__ WE, const int* __restrict__ idx,
              u16* __restrict__ emb,
              const float* __restrict__ W_xh, u16* __restrict__ WxT16,
              u16* __restrict__ WhT,
              const float* __restrict__ W_head, u16* __restrict__ WheadT,
              const float* __restrict__ start, u16* __restrict__ hbuf,
              unsigned* __restrict__ sync) {
  __shared__ float tile[32][33];
  const int b = blockIdx.x;
  const int tid = threadIdx.x;
  if (b < 32768) {
    const int row = idx[b];
    const float4 v = ((const float4*)(WE + (size_t)row * Ee))[tid];
    ushort4 o;
    o.x = f2h_bits(v.x); o.y = f2h_bits(v.y);
    o.z = f2h_bits(v.z); o.w = f2h_bits(v.w);
    ((ushort4*)(emb + (size_t)b * Ee))[tid] = o;
  } else if (b < 34816) {
    const int s = b - 32768;
    tr_cast_f16(W_xh, WxT16, Ee, Hh, s % 64, s / 64, tid, tile);
  } else if (b < 38912) {
    const int s = b - 34816;
    tr_cast_f16(W_xh + (size_t)Ee * Hh, WhT, Hh, Hh, s % 64, s / 64, tid, tile);
  } else if (b < 55296) {
    const int s = b - 38912;
    tr_cast_f16(W_head, WheadT, Hh, Vv, s % 256, s / 256, tid, tile);
  } else {
    const int s = b - 55296;
    #pragma unroll
    for (int j = 0; j < 8; ++j) {
      int n = tid * 8 + j;
      hbuf[(size_t)s * 2048 + n] = f2h_bits(start[n]);
    }
    if (s == 0) sync[tid] = 0;   // 256 u32 = all barrier counters
  }
}

// ---------------- GEMM: 256x256 tile, BK=32, 5-buffer counted pipeline ----------
// C[M x N] = A[M x K] * Bt[N x K]^T, f16/bf16 in, f32 accum. 512 thr = 8 waves
// (2M x 4N), per-wave 128x64 out (acc[8][4]). LDS 160KB = 5 buffers x (A 16KB +
// B 16KB). Per K-tile (BK=32): 2 phases (C row-half x K=32, 16 MFMA each).
// Stage tile t+4 during tile t (A in ph0, B in ph1) -> DMA issued ~4 tiles
// (~600ns) before consumption, covering L3->LDS latency (r12's t+3 left a
// ~200-400ns stall). Target buffer (t+4)%5 = (t-1)%5: read at tile t-1, all
// its ds_reads complete before t-1's MFMAs (lgkmcnt0) which precede t-1's end
// barrier; stage issues after that barrier -> overwrite race impossible.
// vmcnt(14) (derived): at tile T ph0 after issuing A(T+4), the newest 14
// outstanding loads are exactly stages (T+1..T+4) [7 STG x 2]; <=14 remaining
// forces B(T), A(T) and older landed. Ph1 after B(T+4): newest 14 = stages
// B(T+1)..B(T+4) side -> A(T) and older landed. Tail: vmcnt(0).
// LDS layout per tile: [16-row-block][K-granule][row%16] x 16B — linear DMA
// order IS this layout; frag reads 256B-contiguous per 16 lanes: conflict-free.
// MODE 0: f32 out + bias + fused softmax partials pm/ps[row][bn] (bn = N/256).
// MODE 1: bf16 out t-major [(t*B+b)*N+col] + bias, row = b*T+t.
template <int MODE, int F16>
__global__ __launch_bounds__(512, 2)
void gemm256(const u16* __restrict__ A, const u16* __restrict__ Bt,
             const float* __restrict__ bias, void* __restrict__ outp,
             float* __restrict__ pm, float* __restrict__ ps,
             int M, int N, int K) {
  __shared__ u16 lds[81920];   // 160KB: A buf b at b*8192, B buf b at 40960+b*8192

  const int tid = threadIdx.x;
  const int lane = tid & 63;
  const int w = tid >> 6;          // wave 0..7
  const int wm = w >> 2;           // 0..1 (M half)
  const int wn = w & 3;            // 0..3 (N quarter)
  const int l15 = lane & 15, l16 = lane >> 4;

  // XCD-aware swizzle (nwg % 8 == 0 at both call sites)
  const int nwg = gridDim.x * gridDim.y;
  const int lin = blockIdx.y * gridDim.x + blockIdx.x;
  const int swz = (lin & 7) * (nwg >> 3) + (lin >> 3);
  const int bm = swz % gridDim.x;
  const int bn = swz / gridDim.x;
  const int bm256 = bm * 256, bn256 = bn * 256;

  // staging: wave w covers row-blocks w and 8+w; lane: row = rb*16 + l15,
  // granule g = l16. dest = buf + rb*512 (wave-uniform; HW adds lane*16B).
  const size_t srcLane = (size_t)l15 * K + l16 * 8;
  #define STG(P, R0, kt, base)                                                 \
    {                                                                          \
      gll16((P) + (size_t)((R0) + w * 16) * K + (size_t)(kt) * 32 + srcLane,   \
            &lds[(base) + w * 512]);                                           \
      gll16((P) + (size_t)((R0) + (8 + w) * 16) * K + (size_t)(kt) * 32 + srcLane, \
            &lds[(base) + (8 + w) * 512]);                                     \
    }
  #define ABUF(t) (((t) % 5) * 8192)
  #define BBUF(t) (40960 + ((t) % 5) * 8192)
  #define DSF(base, rbase) \
    (*(const bf16x8*)&lds[(base) + ((rbase) >> 4) * 512 + l16 * 128 + l15 * 8])
  #define MM1(a, b, c)                                                          \
    (F16 ? __builtin_amdgcn_mfma_f32_16x16x32_f16(*(const f16x8*)&(a),          \
                                                  *(const f16x8*)&(b), (c), 0, 0, 0) \
         : __builtin_amdgcn_mfma_f32_16x16x32_bf16((a), (b), (c), 0, 0, 0))

  f32x4 acc[8][4];
  #pragma unroll
  for (int m = 0; m < 8; ++m)
    #pragma unroll
    for (int n = 0; n < 4; ++n)
      acc[m][n] = (f32x4){0.f, 0.f, 0.f, 0.f};

  const int NT = K >> 5;           // K-tiles (64 head, 32 xproj; both > 5)

  // prologue: stage tiles 0..3 into buffers 0..3
  for (int pt = 0; pt < 4; ++pt) {
    STG(A,  bm256, pt, ABUF(pt));
    STG(Bt, bn256, pt, BBUF(pt));
  }
  asm volatile("s_waitcnt vmcnt(0)" ::: "memory");
  __builtin_amdgcn_s_barrier();

  for (int t = 0; t < NT; ++t) {
    const int abase = ABUF(t);
    const int bbase = BBUF(t);
    const bool stg = (t + 4 < NT);
    bf16x8 aR[4], bR[4];

    // ---- phase 0: B frags + A row-half 0, stage A of tile t+4 ----
    #pragma unroll
    for (int j = 0; j < 4; ++j) bR[j] = DSF(bbase, wn * 64 + j * 16);
    #pragma unroll
    for (int i = 0; i < 4; ++i) aR[i] = DSF(abase, wm * 128 + i * 16);
    if (stg) {
      STG(A, bm256, t + 4, ABUF(t + 4));
      asm volatile("s_waitcnt vmcnt(14)" ::: "memory");
    } else {
      asm volatile("s_waitcnt vmcnt(0)" ::: "memory");
    }
    __builtin_amdgcn_s_barrier();
    asm volatile("s_waitcnt lgkmcnt(0)" ::: "memory");
    __builtin_amdgcn_sched_barrier(0);
    __builtin_amdgcn_s_setprio(1);
    #pragma unroll
    for (int i = 0; i < 4; ++i)
      #pragma unroll
      for (int j = 0; j < 4; ++j)
        acc[i][j] = MM1(aR[i], bR[j], acc[i][j]);
    __builtin_amdgcn_s_setprio(0);
    __builtin_amdgcn_s_barrier();

    // ---- phase 1: A row-half 1 (B frags reused from regs), stage B of t+4 ----
    #pragma unroll
    for (int i = 0; i < 4; ++i) aR[i] = DSF(abase, wm * 128 + 64 + i * 16);
    if (stg) {
      STG(Bt, bn256, t + 4, BBUF(t + 4));
      asm volatile("s_waitcnt vmcnt(14)" ::: "memory");
    } else {
      asm volatile("s_waitcnt vmcnt(0)" ::: "memory");
    }
    __builtin_amdgcn_s_barrier();
    asm volatile("s_waitcnt lgkmcnt(0)" ::: "memory");
    __builtin_amdgcn_sched_barrier(0);
    __builtin_amdgcn_s_setprio(1);
    #pragma unroll
    for (int i = 0; i < 4; ++i)
      #pragma unroll
      for (int j = 0; j < 4; ++j)
        acc[4 + i][j] = MM1(aR[i], bR[j], acc[4 + i][j]);
    __builtin_amdgcn_s_setprio(0);
    __builtin_amdgcn_s_barrier();
  }

  // ---- epilogue (last barrier passed; LDS reusable) ----
  const int c0 = bn256 + wn * 64 + l15;
  float bv[4];
  #pragma unroll
  for (int j = 0; j < 4; ++j) bv[j] = bias[c0 + j * 16];

  if (MODE == 0) {
    float* scr = (float*)lds;        // [0..1024) max, [1024..2048) sumexp
    float* outf = (float*)outp;
    #pragma unroll
    for (int fm = 0; fm < 8; ++fm) {
      #pragma unroll
      for (int q = 0; q < 4; ++q) {
        const int rl = wm * 128 + (fm >> 2) * 64 + (fm & 3) * 16 + l16 * 4 + q;
        const int row = bm256 + rl;
        float v0 = acc[fm][0][q] + bv[0];
        float v1 = acc[fm][1][q] + bv[1];
        float v2 = acc[fm][2][q] + bv[2];
        float v3 = acc[fm][3][q] + bv[3];
        outf[(size_t)row * N + c0]      = v0;
        outf[(size_t)row * N + c0 + 16] = v1;
        outf[(size_t)row * N + c0 + 32] = v2;
        outf[(size_t)row * N + c0 + 48] = v3;
        float mx = fmaxf(fmaxf(v0, v1), fmaxf(v2, v3));
        #pragma unroll
        for (int d = 1; d < 16; d <<= 1) mx = fmaxf(mx, __shfl_xor(mx, d, 64));
        float se = expf(v0 - mx) + expf(v1 - mx) + expf(v2 - mx) + expf(v3 - mx);
        #pragma unroll
        for (int d = 1; d < 16; d <<= 1) se += __shfl_xor(se, d, 64);
        if (l15 == 0) {
          scr[wn * 256 + rl] = mx;
          scr[1024 + wn * 256 + rl] = se;
        }
      }
    }
    __syncthreads();
    if (lane < 32) {
      const int rl = w * 32 + lane;
      float m0 = scr[rl], m1 = scr[256 + rl], m2 = scr[512 + rl], m3 = scr[768 + rl];
      float Mx = fmaxf(fmaxf(m0, m1), fmaxf(m2, m3));
      float S = scr[1024 + rl] * expf(m0 - Mx) + scr[1280 + rl] * expf(m1 - Mx)
              + scr[1536 + rl] * expf(m2 - Mx) + scr[1792 + rl] * expf(m3 - Mx);
      const int row = bm256 + rl;
      const int nbn = N >> 8;
      pm[(size_t)row * nbn + bn] = Mx;
      ps[(size_t)row * nbn + bn] = S;
    }
  } else {
    u16* outh = (u16*)outp;
    #pragma unroll
    for (int fm = 0; fm < 8; ++fm) {
      #pragma unroll
      for (int q = 0; q < 4; ++q) {
        const int row = bm256 + wm * 128 + (fm >> 2) * 64 + (fm & 3) * 16 + l16 * 4 + q;
        const int b = row >> 9, t = row & 511;   // row = b*T + t
        u16* dst = outh + ((size_t)t * Bb + b) * N + c0;
        dst[0]  = f2b(acc[fm][0][q] + bv[0]);
        dst[16] = f2b(acc[fm][1][q] + bv[1]);
        dst[32] = f2b(acc[fm][2][q] + bv[2]);
        dst[48] = f2b(acc[fm][3][q] + bv[3]);
      }
    }
  }
  #undef STG
  #undef ABUF
  #undef BBUF
  #undef DSF
  #undef MM1
}

// ---------------- persistent recurrence scan (r11, unchanged) ----------------
__global__ __launch_bounds__(512, 2)
void rnn_scan(const u16* __restrict__ WhT, const u16* __restrict__ xp,
              u16* __restrict__ hbuf, u16* __restrict__ hidden,
              unsigned* __restrict__ sync) {
  __shared__ u16 whi[65536];     // 128KB f16 bits: frag(c2,kt) base (c2*64+kt)*512 u16
  __shared__ float red[4096];    // 16KB: 16 slots x 256 f32

  const int bid = blockIdx.x;
  const int g = bid >> 6;
  const int colg = bid & 63;
  const int rowbase = g * 16;
  const int col0 = colg * 32;
  const int tid = threadIdx.x;
  const int lane = tid & 63;
  const int w = tid >> 6;

  for (int i = tid; i < 8192; i += 512) {
    const int ch = i & 3;
    const int cl = (i >> 2) & 15;
    const int kt = (i >> 6) & 63;
    const int c2 = (i >> 12) & 1;
    bf16x8 v = *(const bf16x8*)(WhT + (size_t)(col0 + c2 * 16 + cl) * 2048 + kt * 32 + ch * 8);
    *(bf16x8*)&whi[(size_t)(c2 * 64 + kt) * 512 + ch * 128 + cl * 8] = v;
  }
  __syncthreads();

  unsigned* cnt = sync + g * 64;
  bool dead = false;
  const int hrow = rowbase + (lane & 15);

  const int ev = w * 64 + lane;
  const int ef = ev >> 8;
  const int ep = ev & 255;
  const int el = ep >> 2, eq = ep & 3;
  const int erow = rowbase + (el & 15);
  const int ecol = col0 + ef * 16 + ((el >> 4) << 2) + eq;

  u16 xv16 = xp[(size_t)erow * 2048 + ecol];

  for (int t = 0; t < Tt; ++t) {
    const u16* hp = hbuf + (size_t)(t & 1) * (64 * 2048);
    u16*       hn = hbuf + (size_t)((t + 1) & 1) * (64 * 2048);

    f16x8 qh[8];
    const u16* hb = hp + (size_t)hrow * 2048 + (lane >> 4) * 8;
    #pragma unroll
    for (int kt = 0; kt < 8; ++kt)
      gload16f(qh[kt], hb + (w * 8 + kt) * 32);
    asm volatile("s_waitcnt vmcnt(0)" ::: "memory");
    __builtin_amdgcn_sched_barrier(0);

    f32x4 a0 = (f32x4){0.f, 0.f, 0.f, 0.f};
    f32x4 a1 = (f32x4){0.f, 0.f, 0.f, 0.f};
    #pragma unroll
    for (int kt = 0; kt < 8; ++kt) {
      const int ktG = w * 8 + kt;
      f16x8 w0 = *(const f16x8*)&whi[(size_t)(0 * 64 + ktG) * 512 + (lane >> 4) * 128 + (lane & 15) * 8];
      f16x8 w1 = *(const f16x8*)&whi[(size_t)(1 * 64 + ktG) * 512 + (lane >> 4) * 128 + (lane & 15) * 8];
      a0 = __builtin_amdgcn_mfma_f32_16x16x32_f16(w0, qh[kt], a0, 0, 0, 0);
      a1 = __builtin_amdgcn_mfma_f32_16x16x32_f16(w1, qh[kt], a1, 0, 0, 0);
    }

    *(f32x4*)&red[(w) * 256 + lane * 4]     = a0;
    *(f32x4*)&red[(8 + w) * 256 + lane * 4] = a1;
    __syncthreads();

    {
      float s = 0.f;
      #pragma unroll
      for (int j = 0; j < 8; ++j)
        s += red[(ef * 8 + j) * 256 + ep];
      float hv = tanhf(s + b2f(xv16));
      u16 hf = f2h_bits(hv);
      gstore2_sc1(hn + (size_t)erow * 2048 + ecol, (unsigned)hf);
      hidden[((size_t)erow * Tt + t) * Hh + ecol] = hf;
    }

    __syncthreads();
    if (t + 1 < Tt)
      xv16 = xp[((size_t)(t + 1) * Bb + erow) * 2048 + ecol];
    if (tid == 0) {
      unsigned old = __hip_atomic_fetch_add(cnt, 1u, __ATOMIC_RELAXED, __HIP_MEMORY_SCOPE_AGENT);
      if (old != (unsigned)(t * 64 + 63) && !dead) {
        unsigned polls = 0;
        while (__hip_atomic_load(cnt, __ATOMIC_RELAXED, __HIP_MEMORY_SCOPE_AGENT)
               < (unsigned)((t + 1) * 64)) {
          __builtin_amdgcn_s_sleep(1);
          if (++polls > 1000000u) { dead = true; break; }
        }
      }
    }
    __syncthreads();
  }
}

// ---------------- loss ----------------

__global__ __launch_bounds__(256)
void nll_from_partials(const float* __restrict__ pm, const float* __restrict__ ps,
                       const float* __restrict__ logits, const int* __restrict__ tgt,
                       float* __restrict__ nll) {
  const int r = blockIdx.x * 4 + (threadIdx.x >> 6);
  const int lane = threadIdx.x & 63;
  float m = (lane < 32) ? pm[(size_t)r * 32 + lane] : -1e30f;
  float s = (lane < 32) ? ps[(size_t)r * 32 + lane] : 0.f;
  float M = wave_max(m);
  float S = wave_sum(s * expf(m - M));
  if (lane == 0) {
    const int tg = tgt[r];
    float o = 0.f;
    if (tg != -1) o = M + logf(S) - logits[(size_t)r * Vv + tg];
    nll[r] = o;
  }
}

__global__ __launch_bounds__(256)
void loss_reduce(const float* __restrict__ nll, const int* __restrict__ tgt,
                 float* __restrict__ out) {
  const int tid = threadIdx.x;
  float s = 0.f, c = 0.f;
  for (int i = tid; i < Bb * Tt; i += 256) {
    s += nll[i];
    c += (tgt[i] != -1) ? 1.f : 0.f;
  }
  s = wave_sum(s);
  c = wave_sum(c);
  __shared__ float as_[4], ac_[4];
  const int w = tid >> 6;
  if ((tid & 63) == 0) { as_[w] = s; ac_[w] = c; }
  __syncthreads();
  if (tid == 0) {
    float S = as_[0] + as_[1] + as_[2] + as_[3];
    float C = ac_[0] + ac_[1] + ac_[2] + ac_[3];
    out[0] = S / fmaxf(C, 1.f);
  }
}

// ---------------- launch ----------------

extern "C" void kernel_launch(void* const* d_in, const int* in_sizes, int n_in,
                              void* d_out, int out_size, void* d_ws, size_t ws_size,
                              hipStream_t stream) {
  const int*   idx    = (const int*)d_in[0];
  const int*   tgt    = (const int*)d_in[1];
  const float* W_E    = (const float*)d_in[2];
  const float* start  = (const float*)d_in[3];
  const float* W_xh   = (const float*)d_in[4];
  const float* b_xh   = (const float*)d_in[5];
  const float* W_head = (const float*)d_in[6];
  const float* b_head = (const float*)d_in[7];

  // workspace layout (~314 MB). emb16 (dead after xproj GEMM) aliases hidden.
  // pm/ps (head-GEMM softmax partials) alias xproj (dead after rnn_scan).
  char* ws = (char*)d_ws;
  u16*      emb16  = (u16*)(ws);                                  // 32768x1024 f16 = 64MB
  u16*      hidden = (u16*)(ws);                                  // 32768x2048 f16 = 128MB (alias)
  u16*      xproj  = (u16*)(ws + (size_t)128 * 1024 * 1024);      // [T][B][H] bf16 = 128MB
  float*    pm     = (float*)(ws + (size_t)128 * 1024 * 1024);    // 32768x32 f32 = 4MB (alias)
  float*    ps     = (float*)(ws + (size_t)136 * 1024 * 1024);    // 32768x32 f32 = 4MB (alias)
  u16*      WheadT = (u16*)(ws + (size_t)256 * 1024 * 1024);      // 8192x2048 f16 = 32MB
  u16*      WhT    = (u16*)(ws + (size_t)288 * 1024 * 1024);      // 2048x2048 f16 = 8MB
  u16*      WxT16  = (u16*)(ws + (size_t)304 * 1024 * 1024);      // 2048x1024 f16 = 4MB
  u16*      hbuf   = (u16*)(ws + (size_t)312 * 1024 * 1024);      // 2x64x2048 f16 = 512KB
  float*    nll    = (float*)(ws + (size_t)313 * 1024 * 1024);    // 32768 f32
  unsigned* sync   = (unsigned*)(ws + (size_t)313 * 1024 * 1024 + 128 * 1024);

  // fused preps (embed, 3 transposes, h0, sync zero) — one launch
  prep_all<<<55360, 256, 0, stream>>>(W_E, idx, emb16, W_xh, WxT16, WhT,
                                      W_head, WheadT, start, hbuf, sync);

  // xproj = emb_f16 @ Wx_f16 + b_xh   (K=1024, f16 MFMA, out bf16 t-major)
  gemm256<1, 1><<<dim3(128, 8), 512, 0, stream>>>(emb16, WxT16, b_xh, xproj, nullptr, nullptr,
                                                  Bb * Tt, Hh, 1024);

  // persistent scan: 256 blocks (1/CU), 512 threads, Wh resident in LDS (f16)
  rnn_scan<<<256, 512, 0, stream>>>(WhT, xproj, hbuf, hidden, sync);

  // logits = hidden_f16 @ Whead_f16 + b_head -> d_out, + fused softmax partials
  gemm256<0, 1><<<dim3(128, 32), 512, 0, stream>>>(hidden, WheadT, b_head, d_out, pm, ps,
                                                   Bb * Tt, Vv, 2048);

  nll_from_partials<<<Bb * Tt / 4, 256, 0, stream>>>(pm, ps, (const float*)d_out, tgt, nll);
  loss_reduce<<<1, 256, 0, stream>>>(nll, tgt, (float*)d_out + ((size_t)out_size - 1));
}